// Round 4
// baseline (43.596 us; speedup 1.0000x reference)
//
#include <hip/hip_runtime.h>

// FFD cubic B-spline flow generation, separable (x -> y -> z), persistent
// pipelined blocks. mesh: [4][3][23][27][23] f32, out: [4][3][160][192][160] f32,
// spacing 8 on all axes -> d=(i&7)/8 (8 weight rows shared by all axes), pivot=i>>3.
//
// 1920 blocks (<=8/CU, all co-resident), each handles 3 consecutive yb tiles.
// Per tile: {stageA(next) | stageC(cur)+stores | BAR | stageB(next) | BAR}.
// Raw s_barrier with lgkmcnt-only drain: stores stay in flight across barriers.

#define SPX 160
#define SPY 192
#define SPZ 160
#define CPX 23
#define CPY 27
#define CPZ 23
#define CZP 25   // padded LDS row stride (odd -> conflict-free-ish strided reads)

// LDS-visibility barrier that does NOT drain vmcnt (stores stay in flight).
#define BAR() do { asm volatile("s_waitcnt lgkmcnt(0)" ::: "memory"); \
                   __builtin_amdgcn_s_barrier(); } while (0)

__global__ __launch_bounds__(256, 8) void ffd_kernel(const float* __restrict__ mesh,
                                                     float* __restrict__ out) {
    const int ybg = blockIdx.x;   // 0..7   (group of 3 yb tiles)
    const int xb  = blockIdx.y;   // 0..19  (x block of 8)
    const int bc  = blockIdx.z;   // 0..11  (b*3 + c)
    const int tid = threadIdx.x;

    __shared__ __align__(16) float wlds[8][4];
    __shared__ float tX[8][4][CZP];        // x-contracted:   [x8][b2][cz]
    __shared__ float tXY[2][8][8][CZP];    // x+y-contracted, double-buffered

    // cubic B-spline weight table for the 8 fractional offsets
    if (tid < 32) {
        int j = tid >> 2, a = tid & 3;
        float d  = (float)j * 0.125f;
        float d2 = d * d, d3 = d2 * d;
        float w;
        if (a == 0)      { float e = 1.0f - d; w = e * e * e * (1.0f / 6.0f); }
        else if (a == 1) { w = 0.5f * d3 - d2 + (2.0f / 3.0f); }
        else if (a == 2) { w = -0.5f * d3 + 0.5f * d2 + 0.5f * d + (1.0f / 6.0f); }
        else             { w = d3 * (1.0f / 6.0f); }
        wlds[j][a] = w;
    }
    __syncthreads();

    const float* mch = mesh + (size_t)bc * (CPX * CPY * CPZ);

    // stage A: contract x from global (mesh is L2-resident) -> tX
    auto stageA = [&](int yb) {
        for (int i = tid; i < 8 * 4 * CPZ; i += 256) {   // 736 outputs
            int cz = i % CPZ;
            int r  = i / CPZ;
            int b2 = r & 3;
            int x8 = r >> 2;
            const float* mp = mch + (size_t)xb * (CPY * CPZ) + (yb + b2) * CPZ + cz;
            float acc = wlds[x8][0] * mp[0]
                      + wlds[x8][1] * mp[CPY * CPZ]
                      + wlds[x8][2] * mp[2 * CPY * CPZ]
                      + wlds[x8][3] * mp[3 * CPY * CPZ];
            tX[x8][b2][cz] = acc;
        }
    };

    // stage B: contract y -> tXY[buf]
    auto stageB = [&](int buf) {
        for (int i = tid; i < 8 * 8 * CPZ; i += 256) {   // 1472 outputs
            int cz = i % CPZ;
            int r  = i / CPZ;
            int y8 = r & 7;
            int x8 = r >> 3;
            float acc = wlds[y8][0] * tX[x8][0][cz]
                      + wlds[y8][1] * tX[x8][1][cz]
                      + wlds[y8][2] * tX[x8][2][cz]
                      + wlds[y8][3] * tX[x8][3][cz];
            tXY[buf][x8][y8][cz] = acc;
        }
    };

    // stage C: expand z and store. 8 lanes per (x8,y8) row, 2 rows per thread.
    // out z = 32k + 4*zt + j  ->  q = 4k + (zt>>1), W rows 4*(zt&1)..+3.
    const int zt = tid & 7;
    const int h  = zt & 1;
    const int qo = zt >> 1;
    const float4 Wr0 = *(const float4*)&wlds[4 * h + 0][0];
    const float4 Wr1 = *(const float4*)&wlds[4 * h + 1][0];
    const float4 Wr2 = *(const float4*)&wlds[4 * h + 2][0];
    const float4 Wr3 = *(const float4*)&wlds[4 * h + 3][0];

    auto stageC = [&](int yb, int buf) {
        float* oblk = out + ((size_t)bc * SPX * SPY
                           + (size_t)(xb * 8) * SPY
                           + (size_t)(yb * 8)) * SPZ;
        #pragma unroll
        for (int pass = 0; pass < 2; ++pass) {
            int row = pass * 32 + (tid >> 3);   // 0..63
            int x8 = row >> 3, y8 = row & 7;
            const float* trow = &tXY[buf][x8][y8][0];
            float* orow = oblk + ((size_t)x8 * SPY + (size_t)y8) * SPZ;
            #pragma unroll
            for (int k = 0; k < 5; ++k) {
                int qa = 4 * k + qo;
                float m0 = trow[qa];
                float m1 = trow[qa + 1];
                float m2 = trow[qa + 2];
                float m3 = trow[qa + 3];
                float4 o;
                o.x = Wr0.x * m0 + Wr0.y * m1 + Wr0.z * m2 + Wr0.w * m3;
                o.y = Wr1.x * m0 + Wr1.y * m1 + Wr1.z * m2 + Wr1.w * m3;
                o.z = Wr2.x * m0 + Wr2.y * m1 + Wr2.z * m2 + Wr2.w * m3;
                o.w = Wr3.x * m0 + Wr3.y * m1 + Wr3.z * m2 + Wr3.w * m3;
                *(float4*)&orow[32 * k + 4 * zt] = o;
            }
        }
    };

    const int yb0 = ybg * 3;

    // prologue: fill tXY[0] for the first tile
    stageA(yb0);
    BAR();
    stageB(0);
    BAR();

    // pipelined main loop: 3 tiles, stores every iteration
    int cur = 0;
    #pragma unroll
    for (int t = 0; t < 3; ++t) {
        if (t < 2) stageA(yb0 + t + 1);   // next tile's x-contraction
        stageC(yb0 + t, cur);             // current tile's stores
        BAR();
        if (t < 2) stageB(cur ^ 1);       // next tile's y-contraction
        BAR();
        cur ^= 1;
    }
}

extern "C" void kernel_launch(void* const* d_in, const int* in_sizes, int n_in,
                              void* d_out, int out_size, void* d_ws, size_t ws_size,
                              hipStream_t stream) {
    const float* mesh = (const float*)d_in[0];
    float* out = (float*)d_out;
    dim3 grid(8, SPX / 8, 4 * 3);   // (8, 20, 12) = 1920 blocks, 3 yb-tiles each
    ffd_kernel<<<grid, 256, 0, stream>>>(mesh, out);
}